// Round 3
// baseline (20933.803 us; speedup 1.0000x reference)
//
#include <hip/hip_runtime.h>

#define NWG    256
#define NTHR   512
#define TSTEPS 512

typedef __attribute__((ext_vector_type(4))) float f32x4;
typedef __attribute__((ext_vector_type(8))) short s16x8;

__device__ __forceinline__ unsigned short f2bf(float f) {
  unsigned u = __float_as_uint(f);
  u = (u + 0x7fffu + ((u >> 16) & 1u)) >> 16;   // RNE bf16
  return (unsigned short)u;
}
__device__ __forceinline__ float sigm(float x) { return 1.f / (1.f + __expf(-x)); }
__device__ __forceinline__ float tanh_f(float x) {
  float e = __expf(-2.f * fabsf(x));
  float t = (1.f - e) / (1.f + e);
  return x >= 0.f ? t : -t;
}

// Chunked bf16 activation layout: element (b, k) at ((k>>3)*64 + b)*8 + (k&7)

__global__ void lstm_init(const float* __restrict__ h0,
                          unsigned short* __restrict__ h0b,
                          unsigned short* __restrict__ h1b,
                          float* __restrict__ outp) {
  int i = blockIdx.x * blockDim.x + threadIdx.x;
  if (i < 128) ((unsigned*)(outp + (size_t)511 * 65536))[i] = 0u;  // barrier counters
  if (i < 65536) {
    int b = i >> 10, j = i & 1023;
    int slot = ((j >> 3) * 64 + b) * 8 + (j & 7);
    h0b[slot] = f2bf(h0[b * 1024 + j]);            // layer-0 initial h -> slot 0
    h1b[slot] = f2bf(h0[65536 + b * 1024 + j]);    // layer-1 initial h -> slot 0
  }
}

// One 16x16 output tile over K=1024: P[b][r] = sum_k act[b][k] * W[r][k].
// W rows in LDS, row-major 1024 bf16, 16B-chunk XOR-swizzled by (row&7).
__device__ __forceinline__ void mm_tile(const unsigned short* __restrict__ act,
                                        const short* __restrict__ wl,
                                        float* __restrict__ Pd,
                                        int mtile, int lane) {
  const int r  = lane & 15;
  const int g4 = lane >> 4;
  const int b  = mtile * 16 + r;
  const short* wrow = wl + r * 1024;
  f32x4 acc = {0.f, 0.f, 0.f, 0.f};
#pragma unroll 8
  for (int kk = 0; kk < 1024; kk += 32) {
    const int kc = (kk >> 3) + g4;
    s16x8 a  = *(const s16x8*)(act + (kc * 64 + b) * 8);
    s16x8 bb = *(const s16x8*)(wrow + ((kc ^ (r & 7)) << 3));
    acc = __builtin_amdgcn_mfma_f32_16x16x32_bf16(a, bb, acc, 0, 0, 0);
  }
  const int m0 = mtile * 16 + g4 * 4;
#pragma unroll
  for (int q = 0; q < 4; ++q) Pd[(m0 + q) * 18 + r] = acc[q];
}

// Grid barrier: 8 distributed counter lines; release+acquire fences on wave 0
// only (L1 is per-CU, L2 per-XCD -> one wave's wbl2/inv covers the wg; the
// trailing __syncthreads orders the other waves behind the invalidate).
__device__ __forceinline__ void gbar(unsigned* cb, unsigned target, int tid, int wg8) {
  __syncthreads();
  if (tid == 0) {
    __threadfence();   // release: write back this XCD's L2
    __hip_atomic_fetch_add(cb + wg8 * 16, 1u, __ATOMIC_RELAXED, __HIP_MEMORY_SCOPE_AGENT);
    for (;;) {
      unsigned s = 0;
#pragma unroll
      for (int i = 0; i < 8; ++i)
        s += __hip_atomic_load(cb + i * 16, __ATOMIC_RELAXED, __HIP_MEMORY_SCOPE_AGENT);
      if (s >= target) break;   // clobbered-by-h1 cells read as huge uints -> pass (correct)
      __builtin_amdgcn_s_sleep(2);
    }
    __threadfence();   // acquire: invalidate L1+L2 so fresh activations are read
  }
  __syncthreads();
}

__global__ void __launch_bounds__(NTHR)
lstm_main(const float* __restrict__ c0,
          const float* __restrict__ w_ih, const float* __restrict__ w_hh,
          const float* __restrict__ b_ih, const float* __restrict__ b_hh,
          const float* __restrict__ out_w, const float* __restrict__ out_b,
          float* __restrict__ outp,
          unsigned short* h0b, unsigned short* h1b) {
  extern __shared__ char smem[];
  short* wlds = (short*)smem;               // 4 mats x [16][1024] bf16 = 128KB
                                            //   block0 = Wf = W_ih0@out_w (fused feedback)
                                            //   block1 = W_hh0, block2 = W_ih1, block3 = W_hh1
  float* P    = (float*)(smem + 131072);    // 2 x [64][18] fp32 partials (also staging scratch)
  float* cls  = P + 2304;                   // c state [2][64][4]
  float* bias = cls + 512;                  // [0..15] L0 fused, [16..31] L1, [32..47] L0 @ t=0

  const int tid  = threadIdx.x;
  const int lane = tid & 63;
  const int w    = tid >> 6;
  const int j0   = blockIdx.x * 4;          // this wg's 4 hidden columns
  const int wg8  = blockIdx.x & 7;
  unsigned* cb   = (unsigned*)(outp + (size_t)511 * 65536);  // counters live in out[511]

  // ---- one-time staging: W_hh0 / W_ih1 / W_hh1 slices fp32->bf16 (swizzled) ----
  {
    int rr = tid >> 5, t32 = tid & 31;      // rr 0..15 = gate*4+col
    int gi = rr >> 2, cc = rr & 3;
    for (int m = 1; m < 4; ++m) {
      const float* src  = ((m & 1) ? w_hh : w_ih) + (size_t)(m >> 1) * (4096 * 1024);
      const float* srow = src + (size_t)(gi * 1024 + j0 + cc) * 1024;
      short* drow = wlds + m * 16384 + rr * 1024;
      for (int c = t32; c < 128; c += 32) {
        float4 lo = *(const float4*)(srow + c * 8);
        float4 hi = *(const float4*)(srow + c * 8 + 4);
        s16x8 v;
        v[0] = (short)f2bf(lo.x); v[1] = (short)f2bf(lo.y);
        v[2] = (short)f2bf(lo.z); v[3] = (short)f2bf(lo.w);
        v[4] = (short)f2bf(hi.x); v[5] = (short)f2bf(hi.y);
        v[6] = (short)f2bf(hi.z); v[7] = (short)f2bf(hi.w);
        *(s16x8*)(drow + ((c ^ (rr & 7)) << 3)) = v;
      }
    }
  }

  // ---- one-time: Wf = W_ih0 @ out_w (this wg's 16 rows), fp32 accum -> bf16 LDS ----
  {
    float accA[16], accB[16];
#pragma unroll
    for (int r = 0; r < 16; ++r) { accA[r] = 0.f; accB[r] = 0.f; }
    const float* wb = w_ih + (size_t)j0 * 1024;
#pragma unroll 2
    for (int j = 0; j < 1024; ++j) {
      float o0 = out_w[(size_t)j * 1024 + tid];
      float o1 = out_w[(size_t)j * 1024 + tid + 512];
#pragma unroll
      for (int r = 0; r < 16; ++r) {
        float wv = wb[(size_t)((r >> 2) * 1024 + (r & 3)) * 1024 + j];
        accA[r] += wv * o0;
        accB[r] += wv * o1;
      }
    }
#pragma unroll
    for (int r = 0; r < 16; ++r) {
      int i0 = r * 1024 + (((tid >> 3) ^ (r & 7)) << 3) + (tid & 7);          // k = tid
      int i1 = r * 1024 + ((((tid + 512) >> 3) ^ (r & 7)) << 3) + (tid & 7);  // k = tid+512
      wlds[i0] = (short)f2bf(accA[r]);
      wlds[i1] = (short)f2bf(accB[r]);
    }
  }

  // ---- one-time: biases (fused L0 needs dot(W_ih0_row, out_b), reduced via P) ----
  {
    int rr = tid >> 5, t32 = tid & 31;
    int row = (rr >> 2) * 1024 + j0 + (rr & 3);
    const float* wrow = w_ih + (size_t)row * 1024;
    float p = 0.f;
    for (int j = t32; j < 1024; j += 32) p += wrow[j] * out_b[j];
    P[rr * 32 + t32] = p;
  }
  __syncthreads();
  if (tid < 16) {
    int row = (tid >> 2) * 1024 + j0 + (tid & 3);
    float d = 0.f;
    for (int u = 0; u < 32; ++u) d += P[tid * 32 + u];
    float bsum = b_ih[row] + b_hh[row];
    bias[32 + tid] = bsum;            // t=0: x is exactly zero -> unfused
    bias[tid]      = bsum + d;        // t>0: + W_ih0 @ out_b
    int row1 = 4096 + row;
    bias[16 + tid] = b_ih[row1] + b_hh[row1];
  }
  if (tid < 256) {                    // cell state (lives in LDS for all 512 steps)
    int b = tid >> 2, c2 = tid & 3;
    cls[b * 4 + c2]       = c0[(size_t)b * 1024 + j0 + c2];
    cls[256 + b * 4 + c2] = c0[(size_t)(64 + b) * 1024 + j0 + c2];
  }
  __syncthreads();

  for (int t = 0; t < TSTEPS; ++t) {
    const int cur = t & 1, nxt = cur ^ 1;
    const unsigned short* h0c = h0b + cur * 65536;
    unsigned short*       h0n = h0b + nxt * 65536;
    const unsigned short* h1c = h1b + cur * 65536;
    unsigned short*       h1n = h1b + nxt * 65536;

    // ---- phase A: L0 gates = h1(t-1) @ Wf^T + h0(t-1) @ W_hh0^T ----
    {
      const int mat = w >> 2, mtile = w & 3;
      mm_tile(mat ? h0c : h1c, wlds + mat * 16384, P + mat * 1152, mtile, lane);
    }
    __syncthreads();
    if (tid < 256) {
      const int b = tid >> 2, c2 = tid & 3;
      const float* p0 = P + b * 18;
      const float* p1 = P + 1152 + b * 18;
      const float  s  = (t == 0) ? 0.f : 1.f;          // x_0 = 0 in the reference
      const float* bs = (t == 0) ? (bias + 32) : bias;
      float iv = s * p0[c2]      + p1[c2]      + bs[c2];
      float fv = s * p0[4 + c2]  + p1[4 + c2]  + bs[4 + c2];
      float gv = s * p0[8 + c2]  + p1[8 + c2]  + bs[8 + c2];
      float ov = s * p0[12 + c2] + p1[12 + c2] + bs[12 + c2];
      float cold = cls[b * 4 + c2];
      float cn = sigm(fv) * cold + sigm(iv) * tanh_f(gv);
      float hn = sigm(ov) * tanh_f(cn);
      cls[b * 4 + c2] = cn;
      const int j = j0 + c2;
      h0n[((j >> 3) * 64 + b) * 8 + (j & 7)] = f2bf(hn);
    }
    gbar(cb, (unsigned)(2 * t + 1) * NWG, tid, wg8);

    // ---- phase B: L1 gates = h0(t) @ W_ih1^T + h1(t-1) @ W_hh1^T ----
    {
      const int mat = w >> 2, mtile = w & 3;
      mm_tile(mat ? h1c : (const unsigned short*)h0n,
              wlds + (2 + mat) * 16384, P + mat * 1152, mtile, lane);
    }
    __syncthreads();
    if (tid < 256) {
      const int b = tid >> 2, c2 = tid & 3;
      const float* p0 = P + b * 18;
      const float* p1 = P + 1152 + b * 18;
      float iv = p0[c2]      + p1[c2]      + bias[16 + c2];
      float fv = p0[4 + c2]  + p1[4 + c2]  + bias[16 + 4 + c2];
      float gv = p0[8 + c2]  + p1[8 + c2]  + bias[16 + 8 + c2];
      float ov = p0[12 + c2] + p1[12 + c2] + bias[16 + 12 + c2];
      float cold = cls[256 + b * 4 + c2];
      float cn = sigm(fv) * cold + sigm(iv) * tanh_f(gv);
      float hn = sigm(ov) * tanh_f(cn);
      cls[256 + b * 4 + c2] = cn;
      const int j = j0 + c2;
      h1n[((j >> 3) * 64 + b) * 8 + (j & 7)] = f2bf(hn);
      outp[(size_t)t * 65536 + (size_t)b * 1024 + j] = hn;   // fp32 output
    }
    if (t != TSTEPS - 1)
      gbar(cb, (unsigned)(2 * t + 2) * NWG, tid, wg8);       // no barrier after last step
  }
}

extern "C" void kernel_launch(void* const* d_in, const int* in_sizes, int n_in,
                              void* d_out, int out_size, void* d_ws, size_t ws_size,
                              hipStream_t stream) {
  const float* h0   = (const float*)d_in[0];
  const float* c0   = (const float*)d_in[1];
  const float* w_ih = (const float*)d_in[2];
  const float* w_hh = (const float*)d_in[3];
  const float* b_ih = (const float*)d_in[4];
  const float* b_hh = (const float*)d_in[5];
  const float* ow   = (const float*)d_in[6];
  const float* ob   = (const float*)d_in[7];

  // ws usage: exactly 512 KiB (4 x 128KB bf16 activation slots), nothing else.
  unsigned short* h0b = (unsigned short*)d_ws;   // 2 slots
  unsigned short* h1b = h0b + 2 * 65536;         // 2 slots

  (void)hipFuncSetAttribute((const void*)lstm_main,
                            hipFuncAttributeMaxDynamicSharedMemorySize, 142528);

  lstm_init<<<256, 256, 0, stream>>>(h0, h0b, h1b, (float*)d_out);
  lstm_main<<<NWG, NTHR, 142528, stream>>>(c0, w_ih, w_hh, b_ih, b_hh, ow, ob,
                                           (float*)d_out, h0b, h1b);
}

// Round 4
// 7484.089 us; speedup vs baseline: 2.7971x; 2.7971x over previous
//
#include <hip/hip_runtime.h>

#define NWG    256
#define NTHR   512
#define TSTEPS 512

typedef __attribute__((ext_vector_type(4))) float f32x4;
typedef __attribute__((ext_vector_type(8))) short s16x8;

__device__ __forceinline__ unsigned short f2bf(float f) {
  unsigned u = __float_as_uint(f);
  u = (u + 0x7fffu + ((u >> 16) & 1u)) >> 16;   // RNE bf16
  return (unsigned short)u;
}
__device__ __forceinline__ float sigm(float x) { return 1.f / (1.f + __expf(-x)); }
__device__ __forceinline__ float tanh_f(float x) {
  float e = __expf(-2.f * fabsf(x));
  float t = (1.f - e) / (1.f + e);
  return x >= 0.f ? t : -t;
}

// Chunked bf16 activation layout: element (b, k) at ((k>>3)*64 + b)*8 + (k&7)

__global__ void lstm_init(const float* __restrict__ h0,
                          unsigned short* __restrict__ h0b,
                          unsigned short* __restrict__ h1b,
                          float* __restrict__ outp) {
  int i = blockIdx.x * blockDim.x + threadIdx.x;
  if (i < 128) ((unsigned*)(outp + (size_t)511 * 65536))[i] = 0u;  // barrier counters
  if (i < 65536) {
    int b = i >> 10, j = i & 1023;
    int slot = ((j >> 3) * 64 + b) * 8 + (j & 7);
    h0b[slot] = f2bf(h0[b * 1024 + j]);            // layer-0 initial h -> slot 0
    h1b[slot] = f2bf(h0[65536 + b * 1024 + j]);    // layer-1 initial h -> slot 0
  }
}

// One 16x16 output tile over K=1024: P[b][r] = sum_k act[b][k] * W[r][k].
// W rows in LDS, row-major 1024 bf16, 16B-chunk XOR-swizzled by (row&7).
__device__ __forceinline__ void mm_tile(const unsigned short* __restrict__ act,
                                        const short* __restrict__ wl,
                                        float* __restrict__ Pd,
                                        int mtile, int lane) {
  const int r  = lane & 15;
  const int g4 = lane >> 4;
  const int b  = mtile * 16 + r;
  const short* wrow = wl + r * 1024;
  f32x4 acc = {0.f, 0.f, 0.f, 0.f};
#pragma unroll 8
  for (int kk = 0; kk < 1024; kk += 32) {
    const int kc = (kk >> 3) + g4;
    s16x8 a  = *(const s16x8*)(act + (kc * 64 + b) * 8);
    s16x8 bb = *(const s16x8*)(wrow + ((kc ^ (r & 7)) << 3));
    acc = __builtin_amdgcn_mfma_f32_16x16x32_bf16(a, bb, acc, 0, 0, 0);
  }
  const int m0 = mtile * 16 + g4 * 4;
#pragma unroll
  for (int q = 0; q < 4; ++q) Pd[(m0 + q) * 18 + r] = acc[q];
}

// Grid barrier, cheap-fence edition.
// Cross-wg payloads (h state, output) were stored write-through (agent-scope
// relaxed atomic stores -> sc0|sc1, bypass L1/L2). The __syncthreads below
// drains vmcnt for all waves, so retired stores are already device-visible:
// NO release writeback (buffer_wbl2) needed. Arrival is a relaxed agent
// atomic; after the spin, an acquire-only fence (buffer_inv, no L2 scan-
// writeback) run by wave 0 invalidates this CU's L1 + XCD's L2 so the plain
// (cacheable, XCD-shared) activation loads that follow see fresh data.
__device__ __forceinline__ void gbar(unsigned* cb, unsigned target, int tid, int wg8) {
  __syncthreads();   // drains vmcnt(0) for every wave (compiler-enforced)
  if (tid == 0) {
    __hip_atomic_fetch_add(cb + wg8 * 16, 1u, __ATOMIC_RELAXED, __HIP_MEMORY_SCOPE_AGENT);
    for (;;) {
      unsigned s = 0;
#pragma unroll
      for (int i = 0; i < 8; ++i)
        s += __hip_atomic_load(cb + i * 16, __ATOMIC_RELAXED, __HIP_MEMORY_SCOPE_AGENT);
      if (s >= target) break;   // clobbered-by-h1 cells read as huge uints -> pass (correct)
      __builtin_amdgcn_s_sleep(2);
    }
    __builtin_amdgcn_fence(__ATOMIC_ACQUIRE, "agent");  // buffer_inv only
  }
  __syncthreads();
}

__global__ void __launch_bounds__(NTHR)
lstm_main(const float* __restrict__ c0,
          const float* __restrict__ w_ih, const float* __restrict__ w_hh,
          const float* __restrict__ b_ih, const float* __restrict__ b_hh,
          const float* __restrict__ out_w, const float* __restrict__ out_b,
          float* __restrict__ outp,
          unsigned short* h0b, unsigned short* h1b) {
  extern __shared__ char smem[];
  short* wlds = (short*)smem;               // 4 mats x [16][1024] bf16 = 128KB
                                            //   block0 = Wf = W_ih0@out_w (fused feedback)
                                            //   block1 = W_hh0, block2 = W_ih1, block3 = W_hh1
  float* P    = (float*)(smem + 131072);    // 2 x [64][18] fp32 partials (also staging scratch)
  float* cls  = P + 2304;                   // c state [2][64][4]
  float* bias = cls + 512;                  // [0..15] L0 fused, [16..31] L1, [32..47] L0 @ t=0

  const int tid  = threadIdx.x;
  const int lane = tid & 63;
  const int w    = tid >> 6;
  const int j0   = blockIdx.x * 4;          // this wg's 4 hidden columns
  const int wg8  = blockIdx.x & 7;
  unsigned* cb   = (unsigned*)(outp + (size_t)511 * 65536);  // counters live in out[511]

  // ---- one-time staging: W_hh0 / W_ih1 / W_hh1 slices fp32->bf16 (swizzled) ----
  {
    int rr = tid >> 5, t32 = tid & 31;      // rr 0..15 = gate*4+col
    int gi = rr >> 2, cc = rr & 3;
    for (int m = 1; m < 4; ++m) {
      const float* src  = ((m & 1) ? w_hh : w_ih) + (size_t)(m >> 1) * (4096 * 1024);
      const float* srow = src + (size_t)(gi * 1024 + j0 + cc) * 1024;
      short* drow = wlds + m * 16384 + rr * 1024;
      for (int c = t32; c < 128; c += 32) {
        float4 lo = *(const float4*)(srow + c * 8);
        float4 hi = *(const float4*)(srow + c * 8 + 4);
        s16x8 v;
        v[0] = (short)f2bf(lo.x); v[1] = (short)f2bf(lo.y);
        v[2] = (short)f2bf(lo.z); v[3] = (short)f2bf(lo.w);
        v[4] = (short)f2bf(hi.x); v[5] = (short)f2bf(hi.y);
        v[6] = (short)f2bf(hi.z); v[7] = (short)f2bf(hi.w);
        *(s16x8*)(drow + ((c ^ (rr & 7)) << 3)) = v;
      }
    }
  }

  // ---- one-time: Wf = W_ih0 @ out_w (this wg's 16 rows), fp32 accum -> bf16 LDS ----
  {
    float accA[16], accB[16];
#pragma unroll
    for (int r = 0; r < 16; ++r) { accA[r] = 0.f; accB[r] = 0.f; }
    const float* wb = w_ih + (size_t)j0 * 1024;
#pragma unroll 2
    for (int j = 0; j < 1024; ++j) {
      float o0 = out_w[(size_t)j * 1024 + tid];
      float o1 = out_w[(size_t)j * 1024 + tid + 512];
#pragma unroll
      for (int r = 0; r < 16; ++r) {
        float wv = wb[(size_t)((r >> 2) * 1024 + (r & 3)) * 1024 + j];
        accA[r] += wv * o0;
        accB[r] += wv * o1;
      }
    }
#pragma unroll
    for (int r = 0; r < 16; ++r) {
      int i0 = r * 1024 + (((tid >> 3) ^ (r & 7)) << 3) + (tid & 7);          // k = tid
      int i1 = r * 1024 + ((((tid + 512) >> 3) ^ (r & 7)) << 3) + (tid & 7);  // k = tid+512
      wlds[i0] = (short)f2bf(accA[r]);
      wlds[i1] = (short)f2bf(accB[r]);
    }
  }

  // ---- one-time: biases (fused L0 needs dot(W_ih0_row, out_b), reduced via P) ----
  {
    int rr = tid >> 5, t32 = tid & 31;
    int row = (rr >> 2) * 1024 + j0 + (rr & 3);
    const float* wrow = w_ih + (size_t)row * 1024;
    float p = 0.f;
    for (int j = t32; j < 1024; j += 32) p += wrow[j] * out_b[j];
    P[rr * 32 + t32] = p;
  }
  __syncthreads();
  if (tid < 16) {
    int row = (tid >> 2) * 1024 + j0 + (tid & 3);
    float d = 0.f;
    for (int u = 0; u < 32; ++u) d += P[tid * 32 + u];
    float bsum = b_ih[row] + b_hh[row];
    bias[32 + tid] = bsum;            // t=0: x is exactly zero -> unfused
    bias[tid]      = bsum + d;        // t>0: + W_ih0 @ out_b
    int row1 = 4096 + row;
    bias[16 + tid] = b_ih[row1] + b_hh[row1];
  }
  if (tid < 256) {                    // cell state (lives in LDS for all 512 steps)
    int b = tid >> 2, c2 = tid & 3;
    cls[b * 4 + c2]       = c0[(size_t)b * 1024 + j0 + c2];
    cls[256 + b * 4 + c2] = c0[(size_t)(64 + b) * 1024 + j0 + c2];
  }
  __syncthreads();

  for (int t = 0; t < TSTEPS; ++t) {
    const int cur = t & 1, nxt = cur ^ 1;
    const unsigned short* h0c = h0b + cur * 65536;
    unsigned short*       h0n = h0b + nxt * 65536;
    const unsigned short* h1c = h1b + cur * 65536;
    unsigned short*       h1n = h1b + nxt * 65536;

    // ---- phase A: L0 gates = h1(t-1) @ Wf^T + h0(t-1) @ W_hh0^T ----
    {
      const int mat = w >> 2, mtile = w & 3;
      mm_tile(mat ? h0c : h1c, wlds + mat * 16384, P + mat * 1152, mtile, lane);
    }
    __syncthreads();
    if (tid < 256) {
      const int b = tid >> 2, c2 = tid & 3;
      const float* p0 = P + b * 18;
      const float* p1 = P + 1152 + b * 18;
      const float  s  = (t == 0) ? 0.f : 1.f;          // x_0 = 0 in the reference
      const float* bs = (t == 0) ? (bias + 32) : bias;
      float iv = s * p0[c2]      + p1[c2]      + bs[c2];
      float fv = s * p0[4 + c2]  + p1[4 + c2]  + bs[4 + c2];
      float gv = s * p0[8 + c2]  + p1[8 + c2]  + bs[8 + c2];
      float ov = s * p0[12 + c2] + p1[12 + c2] + bs[12 + c2];
      float cold = cls[b * 4 + c2];
      float cn = sigm(fv) * cold + sigm(iv) * tanh_f(gv);
      float hn = sigm(ov) * tanh_f(cn);
      cls[b * 4 + c2] = cn;
      const int j = j0 + c2;
      // write-through (sc0|sc1) store: device-visible once vmcnt retires
      __hip_atomic_store(h0n + ((j >> 3) * 64 + b) * 8 + (j & 7), f2bf(hn),
                         __ATOMIC_RELAXED, __HIP_MEMORY_SCOPE_AGENT);
    }
    gbar(cb, (unsigned)(2 * t + 1) * NWG, tid, wg8);

    // ---- phase B: L1 gates = h0(t) @ W_ih1^T + h1(t-1) @ W_hh1^T ----
    {
      const int mat = w >> 2, mtile = w & 3;
      mm_tile(mat ? h1c : (const unsigned short*)h0n,
              wlds + (2 + mat) * 16384, P + mat * 1152, mtile, lane);
    }
    __syncthreads();
    if (tid < 256) {
      const int b = tid >> 2, c2 = tid & 3;
      const float* p0 = P + b * 18;
      const float* p1 = P + 1152 + b * 18;
      float iv = p0[c2]      + p1[c2]      + bias[16 + c2];
      float fv = p0[4 + c2]  + p1[4 + c2]  + bias[16 + 4 + c2];
      float gv = p0[8 + c2]  + p1[8 + c2]  + bias[16 + 8 + c2];
      float ov = p0[12 + c2] + p1[12 + c2] + bias[16 + 12 + c2];
      float cold = cls[256 + b * 4 + c2];
      float cn = sigm(fv) * cold + sigm(iv) * tanh_f(gv);
      float hn = sigm(ov) * tanh_f(cn);
      cls[256 + b * 4 + c2] = cn;
      const int j = j0 + c2;
      __hip_atomic_store(h1n + ((j >> 3) * 64 + b) * 8 + (j & 7), f2bf(hn),
                         __ATOMIC_RELAXED, __HIP_MEMORY_SCOPE_AGENT);
      // output also write-through so L2 never holds dirty lines buffer_inv could touch
      __hip_atomic_store(outp + (size_t)t * 65536 + (size_t)b * 1024 + j, hn,
                         __ATOMIC_RELAXED, __HIP_MEMORY_SCOPE_AGENT);
    }
    if (t != TSTEPS - 1)
      gbar(cb, (unsigned)(2 * t + 2) * NWG, tid, wg8);       // no barrier after last step
  }
}

extern "C" void kernel_launch(void* const* d_in, const int* in_sizes, int n_in,
                              void* d_out, int out_size, void* d_ws, size_t ws_size,
                              hipStream_t stream) {
  const float* h0   = (const float*)d_in[0];
  const float* c0   = (const float*)d_in[1];
  const float* w_ih = (const float*)d_in[2];
  const float* w_hh = (const float*)d_in[3];
  const float* b_ih = (const float*)d_in[4];
  const float* b_hh = (const float*)d_in[5];
  const float* ow   = (const float*)d_in[6];
  const float* ob   = (const float*)d_in[7];

  // ws usage: exactly 512 KiB (4 x 128KB bf16 activation slots), nothing else.
  unsigned short* h0b = (unsigned short*)d_ws;   // 2 slots
  unsigned short* h1b = h0b + 2 * 65536;         // 2 slots

  (void)hipFuncSetAttribute((const void*)lstm_main,
                            hipFuncAttributeMaxDynamicSharedMemorySize, 142528);

  lstm_init<<<256, 256, 0, stream>>>(h0, h0b, h1b, (float*)d_out);
  lstm_main<<<NWG, NTHR, 142528, stream>>>(c0, w_ih, w_hh, b_ih, b_hh, ow, ob,
                                           (float*)d_out, h0b, h1b);
}

// Round 5
// 5775.906 us; speedup vs baseline: 3.6243x; 1.2957x over previous
//
#include <hip/hip_runtime.h>

#define NWG    256
#define NTHR   512
#define TSTEPS 512

typedef __attribute__((ext_vector_type(4))) float f32x4;
typedef __attribute__((ext_vector_type(8))) short s16x8;

__device__ __forceinline__ unsigned short f2bf(float f) {
  unsigned u = __float_as_uint(f);
  u = (u + 0x7fffu + ((u >> 16) & 1u)) >> 16;   // RNE bf16
  return (unsigned short)u;
}
__device__ __forceinline__ float sigm(float x) { return 1.f / (1.f + __expf(-x)); }
__device__ __forceinline__ float tanh_f(float x) {
  float e = __expf(-2.f * fabsf(x));
  float t = (1.f - e) / (1.f + e);
  return x >= 0.f ? t : -t;
}

// Chunked bf16 activation layout: element (b, k) at ((k>>3)*64 + b)*8 + (k&7)

__global__ void lstm_init(const float* __restrict__ h0,
                          unsigned short* __restrict__ h0b,
                          unsigned short* __restrict__ h1b,
                          float* __restrict__ outp) {
  int i = blockIdx.x * blockDim.x + threadIdx.x;
  if (i < 128) ((unsigned*)(outp + (size_t)511 * 65536))[i] = 0u;  // barrier counters
  if (i < 65536) {
    int b = i >> 10, j = i & 1023;
    int slot = ((j >> 3) * 64 + b) * 8 + (j & 7);
    h0b[slot] = f2bf(h0[b * 1024 + j]);            // layer-0 initial h -> slot 0
    h1b[slot] = f2bf(h0[65536 + b * 1024 + j]);    // layer-1 initial h -> slot 0
  }
}

// Half-K 16x16 tile: P[b][r] += act[b][k] * W[r][k] over k in [kbeg, kbeg+512).
// W rows in LDS, row-major 1024 bf16, 16B-chunk XOR-swizzled by (row&7).
__device__ __forceinline__ void mm_tile(const unsigned short* __restrict__ act,
                                        const short* __restrict__ wl,
                                        float* __restrict__ Pd,
                                        int mtile, int kbeg, int lane) {
  const int r  = lane & 15;
  const int g4 = lane >> 4;
  const int b  = mtile * 16 + r;
  const short* wrow = wl + r * 1024;
  f32x4 acc = {0.f, 0.f, 0.f, 0.f};
#pragma unroll 8
  for (int kk = kbeg; kk < kbeg + 512; kk += 32) {
    const int kc = (kk >> 3) + g4;
    s16x8 a  = *(const s16x8*)(act + (kc * 64 + b) * 8);
    s16x8 bb = *(const s16x8*)(wrow + ((kc ^ (r & 7)) << 3));
    acc = __builtin_amdgcn_mfma_f32_16x16x32_bf16(a, bb, acc, 0, 0, 0);
  }
  const int m0 = mtile * 16 + g4 * 4;
#pragma unroll
  for (int q = 0; q < 4; ++q) Pd[(m0 + q) * 18 + r] = acc[q];
}

// Split grid barrier. garrive: syncthreads (drains all waves' sc1 stores ->
// coherence point) then one relaxed agent add. gwait: wave0 spins on the 8
// counter lines (per-line check, robust to out[511] clobber at the final
// phase: any clobbered cell reads as a huge uint), then acquire fence
// (buffer_inv only, no L2 writeback scan), then syncthreads releases the wg.
__device__ __forceinline__ void garrive(unsigned* cb, int tid, int wg8) {
  __syncthreads();
  if (tid == 0)
    __hip_atomic_fetch_add(cb + wg8 * 16, 1u, __ATOMIC_RELAXED, __HIP_MEMORY_SCOPE_AGENT);
}
__device__ __forceinline__ void gwait(unsigned* cb, unsigned tgt_line, int tid) {
  if (tid == 0) {
    for (;;) {
      int ok = 1;
#pragma unroll
      for (int i = 0; i < 8; ++i) {
        unsigned v = __hip_atomic_load(cb + i * 16, __ATOMIC_RELAXED, __HIP_MEMORY_SCOPE_AGENT);
        if (v < tgt_line && v < 0x01000000u) ok = 0;
      }
      if (ok) break;
      __builtin_amdgcn_s_sleep(1);
    }
    __builtin_amdgcn_fence(__ATOMIC_ACQUIRE, "agent");  // buffer_inv only
  }
  __syncthreads();
}

__global__ void __launch_bounds__(NTHR)
lstm_main(const float* __restrict__ c0,
          const float* __restrict__ w_ih, const float* __restrict__ w_hh,
          const float* __restrict__ b_ih, const float* __restrict__ b_hh,
          const float* __restrict__ out_w, const float* __restrict__ out_b,
          float* __restrict__ outp,
          unsigned short* h0b, unsigned short* h1b) {
  extern __shared__ char smem[];
  short* wlds = (short*)smem;               // 4 mats x [16][1024] bf16 = 128KB
                                            //   block0 = Wf = W_ih0@out_w (fused feedback)
                                            //   block1 = W_hh0, block2 = W_ih1, block3 = W_hh1
  float* P    = (float*)(smem + 131072);    // 4 x [64][18] fp32 partials (hot lo/hi, warm lo/hi)
  float* cls  = P + 4608;                   // c state [2][64][4]
  float* bias = cls + 512;                  // [0..15] L0 fused, [16..31] L1, [32..47] L0 @ t=0

  const int tid  = threadIdx.x;
  const int lane = tid & 63;
  const int w    = tid >> 6;
  const int mtile = w & 3;                  // batch tile
  const int kbeg  = (w >> 2) * 512;         // K half
  const int j0   = blockIdx.x * 4;          // this wg's 4 hidden columns
  const int wg8  = blockIdx.x & 7;
  unsigned* cb   = (unsigned*)(outp + (size_t)511 * 65536);  // counters live in out[511]

  // ---- one-time staging: W_hh0 / W_ih1 / W_hh1 slices fp32->bf16 (swizzled) ----
  {
    int rr = tid >> 5, t32 = tid & 31;      // rr 0..15 = gate*4+col
    int gi = rr >> 2, cc = rr & 3;
    for (int m = 1; m < 4; ++m) {
      const float* src  = ((m & 1) ? w_hh : w_ih) + (size_t)(m >> 1) * (4096 * 1024);
      const float* srow = src + (size_t)(gi * 1024 + j0 + cc) * 1024;
      short* drow = wlds + m * 16384 + rr * 1024;
      for (int c = t32; c < 128; c += 32) {
        float4 lo = *(const float4*)(srow + c * 8);
        float4 hi = *(const float4*)(srow + c * 8 + 4);
        s16x8 v;
        v[0] = (short)f2bf(lo.x); v[1] = (short)f2bf(lo.y);
        v[2] = (short)f2bf(lo.z); v[3] = (short)f2bf(lo.w);
        v[4] = (short)f2bf(hi.x); v[5] = (short)f2bf(hi.y);
        v[6] = (short)f2bf(hi.z); v[7] = (short)f2bf(hi.w);
        *(s16x8*)(drow + ((c ^ (rr & 7)) << 3)) = v;
      }
    }
  }

  // ---- one-time: Wf = W_ih0 @ out_w (this wg's 16 rows), fp32 accum -> bf16 LDS ----
  {
    float accA[16], accB[16];
#pragma unroll
    for (int r = 0; r < 16; ++r) { accA[r] = 0.f; accB[r] = 0.f; }
    const float* wb = w_ih + (size_t)j0 * 1024;
#pragma unroll 2
    for (int j = 0; j < 1024; ++j) {
      float o0 = out_w[(size_t)j * 1024 + tid];
      float o1 = out_w[(size_t)j * 1024 + tid + 512];
#pragma unroll
      for (int r = 0; r < 16; ++r) {
        float wv = wb[(size_t)((r >> 2) * 1024 + (r & 3)) * 1024 + j];
        accA[r] += wv * o0;
        accB[r] += wv * o1;
      }
    }
#pragma unroll
    for (int r = 0; r < 16; ++r) {
      int i0 = r * 1024 + (((tid >> 3) ^ (r & 7)) << 3) + (tid & 7);          // k = tid
      int i1 = r * 1024 + ((((tid + 512) >> 3) ^ (r & 7)) << 3) + (tid & 7);  // k = tid+512
      wlds[i0] = (short)f2bf(accA[r]);
      wlds[i1] = (short)f2bf(accB[r]);
    }
  }

  // ---- one-time: biases (fused L0 needs dot(W_ih0_row, out_b), reduced via P) ----
  {
    int rr = tid >> 5, t32 = tid & 31;
    int row = (rr >> 2) * 1024 + j0 + (rr & 3);
    const float* wrow = w_ih + (size_t)row * 1024;
    float p = 0.f;
    for (int j = t32; j < 1024; j += 32) p += wrow[j] * out_b[j];
    P[rr * 32 + t32] = p;
  }
  __syncthreads();
  if (tid < 16) {
    int row = (tid >> 2) * 1024 + j0 + (tid & 3);
    float d = 0.f;
    for (int u = 0; u < 32; ++u) d += P[tid * 32 + u];
    float bsum = b_ih[row] + b_hh[row];
    bias[32 + tid] = bsum;            // t=0: x is exactly zero -> unfused
    bias[tid]      = bsum + d;        // t>0: + W_ih0 @ out_b
    int row1 = 4096 + row;
    bias[16 + tid] = b_ih[row1] + b_hh[row1];
  }
  if (tid < 256) {                    // cell state (lives in LDS for all 512 steps)
    int b = tid >> 2, c2 = tid & 3;
    cls[b * 4 + c2]       = c0[(size_t)b * 1024 + j0 + c2];
    cls[256 + b * 4 + c2] = c0[(size_t)(64 + b) * 1024 + j0 + c2];
  }
  __syncthreads();

  for (int t = 0; t < TSTEPS; ++t) {
    const int cur = t & 1, nxt = cur ^ 1;
    const unsigned short* h0c = h0b + cur * 65536;
    unsigned short*       h0n = h0b + nxt * 65536;
    const unsigned short* h1c = h1b + cur * 65536;
    unsigned short*       h1n = h1b + nxt * 65536;
    const int ph = w >> 2;            // P-buffer k-half index

    // ======== phase A: L0 gates = h1(t-1)@Wf^T [hot] + h0(t-1)@W_hh0^T [warm] ====
    // warm half runs during the barrier wait (operand is >=2 phases old)
    mm_tile(h0c, wlds + 1 * 16384, P + (2 + ph) * 1152, mtile, kbeg, lane);
    if (t) gwait(cb, (unsigned)(2 * t) * 32, tid);     // B(t-1) done everywhere + inv
    mm_tile(h1c, wlds + 0 * 16384, P + ph * 1152, mtile, kbeg, lane);
    __syncthreads();
    if (tid < 256) {
      const int b = tid >> 2, c2 = tid & 3;
      const float* pa = P + b * 18;                    // hot k-halves
      const float* pb = P + 1152 + b * 18;
      const float* pc = P + 2304 + b * 18;             // warm k-halves
      const float* pd = P + 3456 + b * 18;
      const float  s  = (t == 0) ? 0.f : 1.f;          // x_0 = 0 in the reference
      const float* bs = (t == 0) ? (bias + 32) : bias;
      float iv = s * (pa[c2]      + pb[c2])      + pc[c2]      + pd[c2]      + bs[c2];
      float fv = s * (pa[4 + c2]  + pb[4 + c2])  + pc[4 + c2]  + pd[4 + c2]  + bs[4 + c2];
      float gv = s * (pa[8 + c2]  + pb[8 + c2])  + pc[8 + c2]  + pd[8 + c2]  + bs[8 + c2];
      float ov = s * (pa[12 + c2] + pb[12 + c2]) + pc[12 + c2] + pd[12 + c2] + bs[12 + c2];
      float cold = cls[b * 4 + c2];
      float cn = sigm(fv) * cold + sigm(iv) * tanh_f(gv);
      float hn = sigm(ov) * tanh_f(cn);
      cls[b * 4 + c2] = cn;
      const int j = j0 + c2;
      __hip_atomic_store(h0n + ((j >> 3) * 64 + b) * 8 + (j & 7), f2bf(hn),
                         __ATOMIC_RELAXED, __HIP_MEMORY_SCOPE_AGENT);
    }
    garrive(cb, tid, wg8);

    // ======== phase B: L1 gates = h0(t)@W_ih1^T [hot] + h1(t-1)@W_hh1^T [warm] ====
    mm_tile(h1c, wlds + 3 * 16384, P + (2 + ph) * 1152, mtile, kbeg, lane);
    gwait(cb, (unsigned)(2 * t + 1) * 32, tid);        // A(t) done everywhere + inv
    mm_tile((const unsigned short*)h0n, wlds + 2 * 16384, P + ph * 1152, mtile, kbeg, lane);
    __syncthreads();
    if (tid < 256) {
      const int b = tid >> 2, c2 = tid & 3;
      const float* pa = P + b * 18;
      const float* pb = P + 1152 + b * 18;
      const float* pc = P + 2304 + b * 18;
      const float* pd = P + 3456 + b * 18;
      float iv = pa[c2]      + pb[c2]      + pc[c2]      + pd[c2]      + bias[16 + c2];
      float fv = pa[4 + c2]  + pb[4 + c2]  + pc[4 + c2]  + pd[4 + c2]  + bias[16 + 4 + c2];
      float gv = pa[8 + c2]  + pb[8 + c2]  + pc[8 + c2]  + pd[8 + c2]  + bias[16 + 8 + c2];
      float ov = pa[12 + c2] + pb[12 + c2] + pc[12 + c2] + pd[12 + c2] + bias[16 + 12 + c2];
      float cold = cls[256 + b * 4 + c2];
      float cn = sigm(fv) * cold + sigm(iv) * tanh_f(gv);
      float hn = sigm(ov) * tanh_f(cn);
      cls[256 + b * 4 + c2] = cn;
      const int j = j0 + c2;
      __hip_atomic_store(h1n + ((j >> 3) * 64 + b) * 8 + (j & 7), f2bf(hn),
                         __ATOMIC_RELAXED, __HIP_MEMORY_SCOPE_AGENT);
      __hip_atomic_store(outp + (size_t)t * 65536 + (size_t)b * 1024 + j, hn,
                         __ATOMIC_RELAXED, __HIP_MEMORY_SCOPE_AGENT);
    }
    if (t != TSTEPS - 1)
      garrive(cb, tid, wg8);          // no arrival needed after the last step
  }
}

extern "C" void kernel_launch(void* const* d_in, const int* in_sizes, int n_in,
                              void* d_out, int out_size, void* d_ws, size_t ws_size,
                              hipStream_t stream) {
  const float* h0   = (const float*)d_in[0];
  const float* c0   = (const float*)d_in[1];
  const float* w_ih = (const float*)d_in[2];
  const float* w_hh = (const float*)d_in[3];
  const float* b_ih = (const float*)d_in[4];
  const float* b_hh = (const float*)d_in[5];
  const float* ow   = (const float*)d_in[6];
  const float* ob   = (const float*)d_in[7];

  // ws usage: exactly 512 KiB (4 x 128KB bf16 activation slots), nothing else.
  unsigned short* h0b = (unsigned short*)d_ws;   // 2 slots
  unsigned short* h1b = h0b + 2 * 65536;         // 2 slots

  (void)hipFuncSetAttribute((const void*)lstm_main,
                            hipFuncAttributeMaxDynamicSharedMemorySize, 151744);

  lstm_init<<<256, 256, 0, stream>>>(h0, h0b, h1b, (float*)d_out);
  lstm_main<<<NWG, NTHR, 151744, stream>>>(c0, w_ih, w_hh, b_ih, b_hh, ow, ob,
                                           (float*)d_out, h0b, h1b);
}